// Round 8
// baseline (7011.271 us; speedup 1.0000x reference)
//
#include <hip/hip_runtime.h>
#include <math.h>

#define BATCH 4
#define NN 4096
#define DIN 128
#define DE 64
#define KK 16

#define GMAXF 2.9135f   // rigorous upper bound on f32 G = log(-log(q+1e-8))
#define GMINPAD 16.65f  // rigorous: G > -16.64  =>  thr_true <= P16g + 16.65

// ---------------- K1: xe = x @ W + bias (r7-verified golden replica) ----------------
__global__ __launch_bounds__(256) void embed_kernel(
    const float* __restrict__ x, const float* __restrict__ W,
    const float* __restrict__ bias, float* __restrict__ xe) {
#pragma clang fp contract(off)
  __shared__ float wl[DIN][DE];
  __shared__ float xs[4][DIN];
  int t = threadIdx.x;
  for (int i = t * 4; i < DIN * DE; i += 1024)
    *(float4*)&wl[i >> 6][i & 63] = *(const float4*)&W[i];
  {
    int rr = t >> 6, dd = (t & 63) * 2;
    const float* src = x + ((size_t)blockIdx.x * 4 + rr) * DIN + dd;
    xs[rr][dd] = src[0];
    xs[rr][dd + 1] = src[1];
  }
  __syncthreads();
  int w = t >> 6, lane = t & 63;
  float acc = 0.f;
#pragma unroll
  for (int d = 0; d < DIN; ++d)
    acc = __builtin_fmaf(xs[w][d], wl[d][lane], acc);  // sequential FMA chain
  xe[((size_t)blockIdx.x * 4 + w) * DE + lane] = acc + bias[lane];
}

// numpy pairwise sum (n=64, scalar 8-accumulator path) of squares (r7-verified)
static __device__ __forceinline__ float np_pairwise_sq64(const float* a) {
#pragma clang fp contract(off)
  float p[8];
#pragma unroll
  for (int j = 0; j < 8; ++j) { float v = a[j]; p[j] = v * v; }
#pragma unroll
  for (int i = 8; i < 64; i += 8)
#pragma unroll
    for (int j = 0; j < 8; ++j) { float v = a[i + j]; p[j] = p[j] + v * v; }
  return ((p[0] + p[1]) + (p[2] + p[3])) + ((p[4] + p[5]) + (p[6] + p[7]));
}

// ---------------- K2: squared norms (row == col norms) ----------------
__global__ __launch_bounds__(256) void sqnorm_kernel(
    const float* __restrict__ xe, float* __restrict__ sq) {
  int row = blockIdx.x * 256 + threadIdx.x;
  sq[row] = np_pairwise_sq64(xe + (size_t)row * DE);
}

// P[c] = max((sqr+sqc)-2*gram, 0) * s32, gram = sequential FMA over d (golden order).
static __device__ __forceinline__ void gram8(const float4* rowv,
                                             const float* __restrict__ cb,
                                             float sqr, const float* sqc8,
                                             float s32, float* P) {
#pragma clang fp contract(off)
  float acc[8] = {0, 0, 0, 0, 0, 0, 0, 0};
#pragma unroll
  for (int dq = 0; dq < 16; ++dq) {
    float4 rv = rowv[dq];
#pragma unroll
    for (int c = 0; c < 8; ++c) {
      float4 bv = *(const float4*)(cb + (size_t)c * DE + dq * 4);
      float a = acc[c];
      a = __builtin_fmaf(rv.x, bv.x, a);
      a = __builtin_fmaf(rv.y, bv.y, a);
      a = __builtin_fmaf(rv.z, bv.z, a);
      a = __builtin_fmaf(rv.w, bv.w, a);
      acc[c] = a;
    }
  }
#pragma unroll
  for (int c = 0; c < 8; ++c) {
    float u = (sqr + sqc8[c]) - 2.0f * acc[c];
    float D = fmaxf(u, 0.0f);
    P[c] = D * s32;
  }
}

// ---------------- K3: pass A — per-segment top-8 of P (no q, no G) ----------------
template <int SEGS>
__global__ __launch_bounds__(256, 4) void passA_kernel(
    const float* __restrict__ xe, const float* __restrict__ sq,
    const float* __restrict__ temp, float* __restrict__ Ap) {
#pragma clang fp contract(off)
  const int SEGW = NN / SEGS;
  int rg = (int)blockIdx.x / SEGS;
  int sg = (int)blockIdx.x % SEGS;
  int row = rg * 256 + (int)threadIdx.x;
  int b = row >> 12;
  int n = row & (NN - 1);
  const float* xb = xe + (size_t)b * NN * DE;

  float4 rowv[16];
  const float* rp = xb + (size_t)n * DE;
#pragma unroll
  for (int i = 0; i < 16; ++i) rowv[i] = ((const float4*)rp)[i];
  float sqr = sq[row];

  double tc = (double)temp[0];
  float s32 = (float)exp(fmin(fmax(tc, -5.0), 5.0));
  const float* sqb = sq + ((size_t)b << 12);

  float at[8];
#pragma unroll
  for (int k = 0; k < 8; ++k) at[k] = __builtin_inff();

  int base = sg * SEGW;
  for (int cg = base; cg < base + SEGW; cg += 8) {
    float4 s0 = *(const float4*)(sqb + cg);
    float4 s1 = *(const float4*)(sqb + cg + 4);
    float sqc8[8] = {s0.x, s0.y, s0.z, s0.w, s1.x, s1.y, s1.z, s1.w};
    float P[8];
    gram8(rowv, xb + (size_t)cg * DE, sqr, sqc8, s32, P);
#pragma unroll
    for (int c = 0; c < 8; ++c) {
      float v = P[c];
      if (v < at[7]) {
#pragma unroll
        for (int k = 7; k >= 1; --k) {
          bool ltk = v < at[k];
          bool ltk1 = v < at[k - 1];
          at[k] = ltk ? (ltk1 ? at[k - 1] : v) : at[k];
        }
        at[0] = (v < at[0]) ? v : at[0];
      }
    }
  }
  float* dst = Ap + ((size_t)row * SEGS + sg) * 8;
#pragma unroll
  for (int k = 0; k < 8; ++k) dst[k] = at[k];
}

// ---------------- K4: merge A -> thrP[row] = (16th smallest of union) + 16.65 ----------------
template <int SEGS>
__global__ __launch_bounds__(256) void mergeA_kernel(
    const float* __restrict__ Ap, float* __restrict__ thrP) {
  int row = (int)blockIdx.x * 256 + (int)threadIdx.x;
  const float* base = Ap + (size_t)row * SEGS * 8;
  float hv[SEGS];
  int hi[SEGS];
#pragma unroll
  for (int s = 0; s < SEGS; ++s) { hv[s] = base[(size_t)s * 8]; hi[s] = 0; }
  float v16 = 0.f;
#pragma unroll
  for (int k = 0; k < 16; ++k) {
    float best = __builtin_inff();
    int bs = 0;
#pragma unroll
    for (int s = 0; s < SEGS; ++s)
      if (hv[s] < best) { best = hv[s]; bs = s; }
    v16 = best;
#pragma unroll
    for (int s = 0; s < SEGS; ++s)
      if (bs == s) {
        hi[s]++;
        hv[s] = (hi[s] < 8) ? base[(size_t)s * 8 + hi[s]] : __builtin_inff();
      }
  }
  thrP[row] = v16 + GMINPAD;
}

// ---------------- K5: pass B — screened exact top-16 by lq ----------------
template <int SEGS>
__global__ __launch_bounds__(256, 2) void passB_kernel(
    const float* __restrict__ xe, const float* __restrict__ sq,
    const float* __restrict__ q, const float* __restrict__ temp,
    const float* __restrict__ thrPa, float* __restrict__ Bv,
    unsigned short* __restrict__ Bc) {
#pragma clang fp contract(off)
  const int SEGW = NN / SEGS;
  int rg = (int)blockIdx.x / SEGS;
  int sg = (int)blockIdx.x % SEGS;
  int row = rg * 256 + (int)threadIdx.x;
  int b = row >> 12;
  int n = row & (NN - 1);
  const float* xb = xe + (size_t)b * NN * DE;

  float4 rowv[16];
  const float* rp = xb + (size_t)n * DE;
#pragma unroll
  for (int i = 0; i < 16; ++i) rowv[i] = ((const float4*)rp)[i];
  float sqr = sq[row];
  float thrP = thrPa[row];

  double tc = (double)temp[0];
  float s32 = (float)exp(fmin(fmax(tc, -5.0), 5.0));
  const float* sqb = sq + ((size_t)b << 12);
  const float* qrow = q + ((size_t)b * NN + n) * NN;

  float topv[16];
  int topi[16];
#pragma unroll
  for (int k = 0; k < 16; ++k) { topv[k] = __builtin_inff(); topi[k] = 0; }

  int base = sg * SEGW;
  for (int cg = base; cg < base + SEGW; cg += 8) {
    float4 s0 = *(const float4*)(sqb + cg);
    float4 s1 = *(const float4*)(sqb + cg + 4);
    float sqc8[8] = {s0.x, s0.y, s0.z, s0.w, s1.x, s1.y, s1.z, s1.w};
    float P[8];
    gram8(rowv, xb + (size_t)cg * DE, sqr, sqc8, s32, P);

    float thr = fminf(topv[15], thrP);
    unsigned m = 0;
#pragma unroll
    for (int c = 0; c < 8; ++c)
      m |= (unsigned)((P[c] - GMAXF) < thr) << c;

    float p0 = P[0], p1 = P[1], p2 = P[2], p3 = P[3];
    float p4 = P[4], p5 = P[5], p6 = P[6], p7 = P[7];
    while (m) {
      int c = __builtin_ctz(m);
      m &= m - 1;
      float a0 = (c & 1) ? p1 : p0, a1 = (c & 1) ? p3 : p2;
      float a2 = (c & 1) ? p5 : p4, a3 = (c & 1) ? p7 : p6;
      float b0 = (c & 2) ? a1 : a0, b1 = (c & 2) ? a3 : a2;
      float Ps = (c & 4) ? b1 : b0;
      int col = cg + c;
      float qv = qrow[col];
      float t1 = qv + 1e-8f;
      float l1 = (float)log((double)t1);   // correctly-rounded f32 log (r7-verified)
      float G = (float)log((double)(-l1));
      float lq = Ps - G;
      if (lq < topv[15]) {
#pragma unroll
        for (int k = 15; k >= 1; --k) {
          bool ltk = lq < topv[k];
          bool ltk1 = lq < topv[k - 1];
          topv[k] = ltk ? (ltk1 ? topv[k - 1] : lq) : topv[k];
          topi[k] = ltk ? (ltk1 ? topi[k - 1] : col) : topi[k];
        }
        if (lq < topv[0]) { topv[0] = lq; topi[0] = col; }
      }
    }
  }
  float* dv = Bv + ((size_t)row * SEGS + sg) * 16;
  unsigned short* dc = Bc + ((size_t)row * SEGS + sg) * 16;
#pragma unroll
  for (int k = 0; k < 16; ++k) {
    dv[k] = topv[k];
    dc[k] = (unsigned short)topi[k];
  }
}

// ---------------- K6: merge B -> outputs ----------------
template <int SEGS>
__global__ __launch_bounds__(256) void mergeB_kernel(
    const float* __restrict__ Bv, const unsigned short* __restrict__ Bc,
    float* __restrict__ e0, float* __restrict__ e1, float* __restrict__ lp) {
  int row = (int)blockIdx.x * 256 + (int)threadIdx.x;
  int b = row >> 12;
  int n = row & (NN - 1);
  const float* vb = Bv + (size_t)row * SEGS * 16;
  const unsigned short* cbp = Bc + (size_t)row * SEGS * 16;
  float hv[SEGS];
  int hc[SEGS];
  int hi[SEGS];
#pragma unroll
  for (int s = 0; s < SEGS; ++s) {
    hv[s] = vb[(size_t)s * 16];
    hc[s] = cbp[(size_t)s * 16];
    hi[s] = 0;
  }
  size_t o = (size_t)row * KK;
#pragma unroll
  for (int k = 0; k < KK; ++k) {
    float best = __builtin_inff();
    int bs = 0;
#pragma unroll
    for (int s = 0; s < SEGS; ++s)
      if (hv[s] < best) { best = hv[s]; bs = s; }  // strict <: lowest seg on ties
    int bcol = 0;
#pragma unroll
    for (int s = 0; s < SEGS; ++s)
      if (bs == s) bcol = hc[s];
    lp[o + k] = -best;
    e0[o + k] = (float)(bcol + b * NN);
    e1[o + k] = (float)(n + b * NN);
#pragma unroll
    for (int s = 0; s < SEGS; ++s)
      if (bs == s) {
        hi[s]++;
        bool ok = hi[s] < 16;
        hv[s] = ok ? vb[(size_t)s * 16 + hi[s]] : __builtin_inff();
        hc[s] = ok ? (int)cbp[(size_t)s * 16 + hi[s]] : 0;
      }
  }
}

extern "C" void kernel_launch(void* const* d_in, const int* in_sizes, int n_in,
                              void* d_out, int out_size, void* d_ws,
                              size_t ws_size, hipStream_t stream) {
  (void)in_sizes; (void)n_in; (void)out_size;
  const float* x = (const float*)d_in[0];
  // d_in[1] = A (unused placeholder)
  const float* W = (const float*)d_in[2];
  const float* bias = (const float*)d_in[3];
  const float* temp = (const float*)d_in[4];
  const float* q = (const float*)d_in[5];

  float* xe = (float*)d_out;                 // [4,4096,64]
  float* e0 = xe + (size_t)BATCH * NN * DE;  // edges row 0 (indices)
  float* e1 = e0 + (size_t)BATCH * NN * KK;  // edges row 1 (rows)
  float* lp = e1 + (size_t)BATCH * NN * KK;  // logprobs

  const int ROWS = BATCH * NN;  // 16384
  char* ws = (char*)d_ws;
  float* sq = (float*)ws;                  // 64 KB
  float* thrP = (float*)(ws + 65536);      // 64 KB
  char* buf = ws + 131072;
  // need(SEGS) = 128K + SEGS*ROWS*(16*4 + 16*2) ; Ap (SEGS*ROWS*32) aliases Bv
  auto need = [&](size_t s) { return (size_t)131072 + s * (size_t)ROWS * 96; };
  int segs = (ws_size >= need(16)) ? 16
             : (ws_size >= need(8)) ? 8
             : (ws_size >= need(4)) ? 4 : 2;

  embed_kernel<<<BATCH * NN / 4, 256, 0, stream>>>(x, W, bias, xe);
  sqnorm_kernel<<<ROWS / 256, 256, 0, stream>>>(xe, sq);

#define RUN(S)                                                                   \
  {                                                                              \
    float* Ap = (float*)buf;                                                     \
    float* Bv = (float*)buf;                                                     \
    unsigned short* Bc = (unsigned short*)(buf + (size_t)S * ROWS * 64);         \
    passA_kernel<S><<<(ROWS / 256) * S, 256, 0, stream>>>(xe, sq, temp, Ap);     \
    mergeA_kernel<S><<<ROWS / 256, 256, 0, stream>>>(Ap, thrP);                  \
    passB_kernel<S><<<(ROWS / 256) * S, 256, 0, stream>>>(xe, sq, q, temp, thrP, \
                                                          Bv, Bc);               \
    mergeB_kernel<S><<<ROWS / 256, 256, 0, stream>>>(Bv, Bc, e0, e1, lp);        \
  }
  if (segs == 16) RUN(16)
  else if (segs == 8) RUN(8)
  else if (segs == 4) RUN(4)
  else RUN(2)
#undef RUN
}

// Round 9
// 901.633 us; speedup vs baseline: 7.7762x; 7.7762x over previous
//
#include <hip/hip_runtime.h>
#include <math.h>

#define BATCH 4
#define NN 4096
#define DIN 128
#define DE 64
#define KK 16

#define GMAXF 2.9135f   // rigorous upper bound on f32 G = log(-log(q+1e-8))
#define SCRMARG 1e-3f   // logf-screen margin (r7-verified)

// ---------------- K1: xe = x @ W + bias (r7-verified golden replica) ----------------
__global__ __launch_bounds__(256) void embed_kernel(
    const float* __restrict__ x, const float* __restrict__ W,
    const float* __restrict__ bias, float* __restrict__ xe) {
#pragma clang fp contract(off)
  __shared__ float wl[DIN][DE];
  __shared__ float xs[4][DIN];
  int t = threadIdx.x;
  for (int i = t * 4; i < DIN * DE; i += 1024)
    *(float4*)&wl[i >> 6][i & 63] = *(const float4*)&W[i];
  {
    int rr = t >> 6, dd = (t & 63) * 2;
    const float* src = x + ((size_t)blockIdx.x * 4 + rr) * DIN + dd;
    xs[rr][dd] = src[0];
    xs[rr][dd + 1] = src[1];
  }
  __syncthreads();
  int w = t >> 6, lane = t & 63;
  float acc = 0.f;
#pragma unroll
  for (int d = 0; d < DIN; ++d)
    acc = __builtin_fmaf(xs[w][d], wl[d][lane], acc);  // sequential FMA chain
  xe[((size_t)blockIdx.x * 4 + w) * DE + lane] = acc + bias[lane];
}

// numpy pairwise sum (n=64, scalar 8-accumulator path) of squares (r7-verified)
static __device__ __forceinline__ float np_pairwise_sq64(const float* a) {
#pragma clang fp contract(off)
  float p[8];
#pragma unroll
  for (int j = 0; j < 8; ++j) { float v = a[j]; p[j] = v * v; }
#pragma unroll
  for (int i = 8; i < 64; i += 8)
#pragma unroll
    for (int j = 0; j < 8; ++j) { float v = a[i + j]; p[j] = p[j] + v * v; }
  return ((p[0] + p[1]) + (p[2] + p[3])) + ((p[4] + p[5]) + (p[6] + p[7]));
}

// ---------------- K2: squared norms ----------------
__global__ __launch_bounds__(256) void sqnorm_kernel(
    const float* __restrict__ xe, float* __restrict__ sq) {
  int row = blockIdx.x * 256 + threadIdx.x;
  sq[row] = np_pairwise_sq64(xe + (size_t)row * DE);
}

// P[c] = max((sqr+sqc)-2*gram, 0)*s32; gram = sequential FMA d=0..63 (golden order)
static __device__ __forceinline__ void gram8(const float4* rowv,
                                             const float* __restrict__ cb,
                                             float sqr, const float* sqc8,
                                             float s32, float* P) {
#pragma clang fp contract(off)
  float acc[8] = {0, 0, 0, 0, 0, 0, 0, 0};
#pragma unroll
  for (int dq = 0; dq < 16; ++dq) {
    float4 rv = rowv[dq];
#pragma unroll
    for (int c = 0; c < 8; ++c) {
      float4 bv = *(const float4*)(cb + (size_t)c * DE + dq * 4);
      float a = acc[c];
      a = __builtin_fmaf(rv.x, bv.x, a);
      a = __builtin_fmaf(rv.y, bv.y, a);
      a = __builtin_fmaf(rv.z, bv.z, a);
      a = __builtin_fmaf(rv.w, bv.w, a);
      acc[c] = a;
    }
  }
#pragma unroll
  for (int c = 0; c < 8; ++c) {
    float u = (sqr + sqc8[c]) - 2.0f * acc[c];
    float D = fmaxf(u, 0.0f);
    P[c] = D * s32;
  }
}

// ---------------- K3: fused segmented top-16 with lazy exact G ----------------
template <int SEGS>
__global__ __launch_bounds__(256) void topk_seg_kernel(
    const float* __restrict__ xe, const float* __restrict__ sq,
    const float* __restrict__ q, const float* __restrict__ temp,
    float* __restrict__ Bv, unsigned short* __restrict__ Bc) {
#pragma clang fp contract(off)
  const int SEGW = NN / SEGS;
  int rg = (int)blockIdx.x / SEGS;
  int sg = (int)blockIdx.x % SEGS;
  int row = rg * 256 + (int)threadIdx.x;
  int b = row >> 12;
  int n = row & (NN - 1);
  const float* xb = xe + (size_t)b * NN * DE;

  float4 rowv[16];
  const float* rp = xb + (size_t)n * DE;
#pragma unroll
  for (int i = 0; i < 16; ++i) rowv[i] = ((const float4*)rp)[i];
  float sqr = sq[row];

  double tc = (double)temp[0];
  float s32 = (float)exp(fmin(fmax(tc, -5.0), 5.0));
  const float* sqb = sq + ((size_t)b << 12);
  const float* qrow = q + ((size_t)b * NN + n) * NN;

  float topv[16];
  int topi[16];
#pragma unroll
  for (int k = 0; k < 16; ++k) { topv[k] = __builtin_inff(); topi[k] = 0; }

  int base = sg * SEGW;
  for (int cg = base; cg < base + SEGW; cg += 8) {
    float4 s0 = *(const float4*)(sqb + cg);
    float4 s1 = *(const float4*)(sqb + cg + 4);
    float sqc8[8] = {s0.x, s0.y, s0.z, s0.w, s1.x, s1.y, s1.z, s1.w};
    float P[8];
    gram8(rowv, xb + (size_t)cg * DE, sqr, sqc8, s32, P);

    float at15 = topv[15];
    unsigned m = 0;
#pragma unroll
    for (int c = 0; c < 8; ++c)
      m |= (unsigned)((P[c] - GMAXF) < at15) << c;  // sound: P-Gmax <= lq (RN monotone)

    float p0 = P[0], p1 = P[1], p2 = P[2], p3 = P[3];
    float p4 = P[4], p5 = P[5], p6 = P[6], p7 = P[7];
    while (m) {
      int c = __builtin_ctz(m);
      m &= m - 1;
      float a0 = (c & 1) ? p1 : p0, a1 = (c & 1) ? p3 : p2;
      float a2 = (c & 1) ? p5 : p4, a3 = (c & 1) ? p7 : p6;
      float b0 = (c & 2) ? a1 : a0, b1 = (c & 2) ? a3 : a2;
      float Ps = (c & 4) ? b1 : b0;
      float qv = qrow[cg + c];
      float t1 = qv + 1e-8f;
      // cheap screen (device logf, err ~1e-5 << 1e-3 margin; r7-verified)
      float lq_scr = Ps - logf(-logf(t1));
      if (lq_scr < at15 + SCRMARG) {
        float l1 = (float)log((double)t1);  // correctly-rounded f32 log
        float G = (float)log((double)(-l1));
        float lq = Ps - G;
        if (lq < topv[15]) {
          int col = cg + c;
#pragma unroll
          for (int k = 15; k >= 1; --k) {
            bool ltk = lq < topv[k];
            bool ltk1 = lq < topv[k - 1];
            topv[k] = ltk ? (ltk1 ? topv[k - 1] : lq) : topv[k];
            topi[k] = ltk ? (ltk1 ? topi[k - 1] : col) : topi[k];
          }
          if (lq < topv[0]) { topv[0] = lq; topi[0] = col; }
          at15 = topv[15];
        }
      }
    }
  }
  float* dv = Bv + ((size_t)row * SEGS + sg) * 16;
  unsigned short* dc = Bc + ((size_t)row * SEGS + sg) * 16;
#pragma unroll
  for (int k = 0; k < 16; ++k) {
    dv[k] = topv[k];
    dc[k] = (unsigned short)topi[k];
  }
}

// ---------------- K4: merge per-seg lists -> outputs ----------------
template <int SEGS>
__global__ __launch_bounds__(256) void mergeB_kernel(
    const float* __restrict__ Bv, const unsigned short* __restrict__ Bc,
    float* __restrict__ e0, float* __restrict__ e1, float* __restrict__ lp) {
  int row = (int)blockIdx.x * 256 + (int)threadIdx.x;
  int b = row >> 12;
  int n = row & (NN - 1);
  const float* vb = Bv + (size_t)row * SEGS * 16;
  const unsigned short* cbp = Bc + (size_t)row * SEGS * 16;
  float hv[SEGS];
  int hc[SEGS];
  int hi[SEGS];
#pragma unroll
  for (int s = 0; s < SEGS; ++s) {
    hv[s] = vb[(size_t)s * 16];
    hc[s] = cbp[(size_t)s * 16];
    hi[s] = 0;
  }
  size_t o = (size_t)row * KK;
#pragma unroll
  for (int k = 0; k < KK; ++k) {
    float best = __builtin_inff();
    int bs = 0;
#pragma unroll
    for (int s = 0; s < SEGS; ++s)
      if (hv[s] < best) { best = hv[s]; bs = s; }  // strict <: lowest seg on ties
    int bcol = 0;
#pragma unroll
    for (int s = 0; s < SEGS; ++s)
      if (bs == s) bcol = hc[s];
    lp[o + k] = -best;
    e0[o + k] = (float)(bcol + b * NN);
    e1[o + k] = (float)(n + b * NN);
#pragma unroll
    for (int s = 0; s < SEGS; ++s)
      if (bs == s) {
        hi[s]++;
        bool ok = hi[s] < 16;
        hv[s] = ok ? vb[(size_t)s * 16 + hi[s]] : __builtin_inff();
        hc[s] = ok ? (int)cbp[(size_t)s * 16 + hi[s]] : 0;
      }
  }
}

extern "C" void kernel_launch(void* const* d_in, const int* in_sizes, int n_in,
                              void* d_out, int out_size, void* d_ws,
                              size_t ws_size, hipStream_t stream) {
  (void)in_sizes; (void)n_in; (void)out_size;
  const float* x = (const float*)d_in[0];
  // d_in[1] = A (unused placeholder)
  const float* W = (const float*)d_in[2];
  const float* bias = (const float*)d_in[3];
  const float* temp = (const float*)d_in[4];
  const float* q = (const float*)d_in[5];

  float* xe = (float*)d_out;                 // [4,4096,64]
  float* e0 = xe + (size_t)BATCH * NN * DE;  // edges row 0 (indices)
  float* e1 = e0 + (size_t)BATCH * NN * KK;  // edges row 1 (rows)
  float* lp = e1 + (size_t)BATCH * NN * KK;  // logprobs

  const int ROWS = BATCH * NN;  // 16384
  char* ws = (char*)d_ws;
  float* sq = (float*)ws;  // 64 KB
  char* buf = ws + 65536;
  // need(S) = 64K + S*ROWS*(16*4 + 16*2)
  auto need = [&](size_t s) { return (size_t)65536 + s * (size_t)ROWS * 96; };
  int segs = (ws_size >= need(16)) ? 16 : (ws_size >= need(8)) ? 8 : 4;

  embed_kernel<<<BATCH * NN / 4, 256, 0, stream>>>(x, W, bias, xe);
  sqnorm_kernel<<<ROWS / 256, 256, 0, stream>>>(xe, sq);

#define RUN(S)                                                                \
  {                                                                           \
    float* Bv = (float*)buf;                                                  \
    unsigned short* Bc = (unsigned short*)(buf + (size_t)S * ROWS * 64);      \
    topk_seg_kernel<S><<<(ROWS / 256) * S, 256, 0, stream>>>(xe, sq, q, temp, \
                                                             Bv, Bc);         \
    mergeB_kernel<S><<<ROWS / 256, 256, 0, stream>>>(Bv, Bc, e0, e1, lp);     \
  }
  if (segs == 16) RUN(16)
  else if (segs == 8) RUN(8)
  else RUN(4)
#undef RUN
}

// Round 10
// 718.922 us; speedup vs baseline: 9.7525x; 1.2541x over previous
//
#include <hip/hip_runtime.h>
#include <math.h>

#define BATCH 4
#define NN 4096
#define DIN 128
#define DE 64
#define KK 16

#define GMAXF 2.9135f   // rigorous upper bound on f32 G = log(-log(q+1e-8))
#define SCRMARG 1e-3f   // logf-screen margin (r7-verified)

// ---------------- K1: xe = x @ W + bias (r7-verified golden replica) ----------------
__global__ __launch_bounds__(256) void embed_kernel(
    const float* __restrict__ x, const float* __restrict__ W,
    const float* __restrict__ bias, float* __restrict__ xe) {
#pragma clang fp contract(off)
  __shared__ float wl[DIN][DE];
  __shared__ float xs[4][DIN];
  int t = threadIdx.x;
  for (int i = t * 4; i < DIN * DE; i += 1024)
    *(float4*)&wl[i >> 6][i & 63] = *(const float4*)&W[i];
  {
    int rr = t >> 6, dd = (t & 63) * 2;
    const float* src = x + ((size_t)blockIdx.x * 4 + rr) * DIN + dd;
    xs[rr][dd] = src[0];
    xs[rr][dd + 1] = src[1];
  }
  __syncthreads();
  int w = t >> 6, lane = t & 63;
  float acc = 0.f;
#pragma unroll
  for (int d = 0; d < DIN; ++d)
    acc = __builtin_fmaf(xs[w][d], wl[d][lane], acc);  // sequential FMA chain
  xe[((size_t)blockIdx.x * 4 + w) * DE + lane] = acc + bias[lane];
}

// numpy pairwise sum (n=64, scalar 8-accumulator path) of squares (r7-verified)
static __device__ __forceinline__ float np_pairwise_sq64(const float* a) {
#pragma clang fp contract(off)
  float p[8];
#pragma unroll
  for (int j = 0; j < 8; ++j) { float v = a[j]; p[j] = v * v; }
#pragma unroll
  for (int i = 8; i < 64; i += 8)
#pragma unroll
    for (int j = 0; j < 8; ++j) { float v = a[i + j]; p[j] = p[j] + v * v; }
  return ((p[0] + p[1]) + (p[2] + p[3])) + ((p[4] + p[5]) + (p[6] + p[7]));
}

// ---------------- K2: squared norms ----------------
__global__ __launch_bounds__(256) void sqnorm_kernel(
    const float* __restrict__ xe, float* __restrict__ sq) {
  int row = blockIdx.x * 256 + threadIdx.x;
  sq[row] = np_pairwise_sq64(xe + (size_t)row * DE);
}

// ---------------- K3: fused segmented top-16, block-uniform column base ----------------
// Thread = (row, seg). Column tile / sqc addresses derive from blockIdx ONLY ->
// uniformity analysis scalarizes them (s_load + FMA-from-SGPR), freeing the VALU
// for the 512 FMA/group. Math bit-identical to r7-verified chain.
template <int SEGS>
__global__ __launch_bounds__(256) void topk_seg_kernel(
    const float* __restrict__ xe, const float* __restrict__ sq,
    const float* __restrict__ q, const float* __restrict__ temp,
    float* __restrict__ Bv, unsigned short* __restrict__ Bc) {
#pragma clang fp contract(off)
  const int SEGW = NN / SEGS;
  int rg = (int)blockIdx.x / SEGS;
  int sg = (int)blockIdx.x % SEGS;
  // block-uniform batch + row-group base (256 | 4096 => never crosses batch)
  int bu = (rg * 256) >> 12;
  int n0 = (rg * 256) & (NN - 1);
  int n = n0 + (int)threadIdx.x;            // per-lane row within batch
  int row = (bu << 12) + n;                 // per-lane global row
  const float* xb = xe + (size_t)bu * NN * DE;   // UNIFORM
  const float* sqb = sq + ((size_t)bu << 12);    // UNIFORM

  float4 rowv[16];
  const float* rp = xb + (size_t)n * DE;
#pragma unroll
  for (int i = 0; i < 16; ++i) rowv[i] = ((const float4*)rp)[i];
  float sqr = sqb[n];

  double tc = (double)temp[0];
  float s32 = (float)exp(fmin(fmax(tc, -5.0), 5.0));
  const float* qrow = q + ((size_t)bu * NN + n) * NN;

  float topv[16];
  int topi[16];
#pragma unroll
  for (int k = 0; k < 16; ++k) { topv[k] = __builtin_inff(); topi[k] = 0; }

  int base = sg * SEGW;  // uniform
  for (int cg = base; cg < base + SEGW; cg += 8) {
    // uniform sqc loads
    float4 s0 = *(const float4*)(sqb + cg);
    float4 s1 = *(const float4*)(sqb + cg + 4);
    float sqc8[8] = {s0.x, s0.y, s0.z, s0.w, s1.x, s1.y, s1.z, s1.w};

    // gram: sequential FMA d=0..63 (golden order); column operands uniform
    const float* cb = xb + (size_t)cg * DE;  // UNIFORM
    float acc[8] = {0, 0, 0, 0, 0, 0, 0, 0};
#pragma unroll
    for (int dq = 0; dq < 16; ++dq) {
      float4 rv = rowv[dq];
#pragma unroll
      for (int c = 0; c < 8; ++c) {
        float4 bv = *(const float4*)(cb + (size_t)c * DE + dq * 4);  // uniform
        float a = acc[c];
        a = __builtin_fmaf(rv.x, bv.x, a);
        a = __builtin_fmaf(rv.y, bv.y, a);
        a = __builtin_fmaf(rv.z, bv.z, a);
        a = __builtin_fmaf(rv.w, bv.w, a);
        acc[c] = a;
      }
    }
    float P[8];
#pragma unroll
    for (int c = 0; c < 8; ++c) {
      float u = (sqr + sqc8[c]) - 2.0f * acc[c];
      float D = fmaxf(u, 0.0f);
      P[c] = D * s32;
    }

    float at15 = topv[15];
    unsigned m = 0;
#pragma unroll
    for (int c = 0; c < 8; ++c)
      m |= (unsigned)((P[c] - GMAXF) < at15) << c;  // sound prescreen

    float p0 = P[0], p1 = P[1], p2 = P[2], p3 = P[3];
    float p4 = P[4], p5 = P[5], p6 = P[6], p7 = P[7];
    while (m) {
      int c = __builtin_ctz(m);
      m &= m - 1;
      float a0 = (c & 1) ? p1 : p0, a1 = (c & 1) ? p3 : p2;
      float a2 = (c & 1) ? p5 : p4, a3 = (c & 1) ? p7 : p6;
      float b0 = (c & 2) ? a1 : a0, b1 = (c & 2) ? a3 : a2;
      float Ps = (c & 4) ? b1 : b0;
      float qv = qrow[cg + c];
      float t1 = qv + 1e-8f;
      // cheap screen (device logf, err ~1e-5 << 1e-3 margin; r7-verified)
      float lq_scr = Ps - logf(-logf(t1));
      if (lq_scr < at15 + SCRMARG) {
        float l1 = (float)log((double)t1);  // correctly-rounded f32 log
        float G = (float)log((double)(-l1));
        float lq = Ps - G;
        if (lq < topv[15]) {
          int col = cg + c;
#pragma unroll
          for (int k = 15; k >= 1; --k) {
            bool ltk = lq < topv[k];
            bool ltk1 = lq < topv[k - 1];
            topv[k] = ltk ? (ltk1 ? topv[k - 1] : lq) : topv[k];
            topi[k] = ltk ? (ltk1 ? topi[k - 1] : col) : topi[k];
          }
          if (lq < topv[0]) { topv[0] = lq; topi[0] = col; }
          at15 = topv[15];
        }
      }
    }
  }
  float* dv = Bv + ((size_t)row * SEGS + sg) * 16;
  unsigned short* dc = Bc + ((size_t)row * SEGS + sg) * 16;
#pragma unroll
  for (int k = 0; k < 16; ++k) {
    dv[k] = topv[k];
    dc[k] = (unsigned short)topi[k];
  }
}

// ---------------- K4: merge per-seg lists -> outputs ----------------
template <int SEGS>
__global__ __launch_bounds__(256) void mergeB_kernel(
    const float* __restrict__ Bv, const unsigned short* __restrict__ Bc,
    float* __restrict__ e0, float* __restrict__ e1, float* __restrict__ lp) {
  int row = (int)blockIdx.x * 256 + (int)threadIdx.x;
  int b = row >> 12;
  int n = row & (NN - 1);
  const float* vb = Bv + (size_t)row * SEGS * 16;
  const unsigned short* cbp = Bc + (size_t)row * SEGS * 16;
  float hv[SEGS];
  int hc[SEGS];
  int hi[SEGS];
#pragma unroll
  for (int s = 0; s < SEGS; ++s) {
    hv[s] = vb[(size_t)s * 16];
    hc[s] = cbp[(size_t)s * 16];
    hi[s] = 0;
  }
  size_t o = (size_t)row * KK;
#pragma unroll
  for (int k = 0; k < KK; ++k) {
    float best = __builtin_inff();
    int bs = 0;
#pragma unroll
    for (int s = 0; s < SEGS; ++s)
      if (hv[s] < best) { best = hv[s]; bs = s; }  // strict <: lowest seg on ties
    int bcol = 0;
#pragma unroll
    for (int s = 0; s < SEGS; ++s)
      if (bs == s) bcol = hc[s];
    lp[o + k] = -best;
    e0[o + k] = (float)(bcol + b * NN);
    e1[o + k] = (float)(n + b * NN);
#pragma unroll
    for (int s = 0; s < SEGS; ++s)
      if (bs == s) {
        hi[s]++;
        bool ok = hi[s] < 16;
        hv[s] = ok ? vb[(size_t)s * 16 + hi[s]] : __builtin_inff();
        hc[s] = ok ? (int)cbp[(size_t)s * 16 + hi[s]] : 0;
      }
  }
}

extern "C" void kernel_launch(void* const* d_in, const int* in_sizes, int n_in,
                              void* d_out, int out_size, void* d_ws,
                              size_t ws_size, hipStream_t stream) {
  (void)in_sizes; (void)n_in; (void)out_size;
  const float* x = (const float*)d_in[0];
  // d_in[1] = A (unused placeholder)
  const float* W = (const float*)d_in[2];
  const float* bias = (const float*)d_in[3];
  const float* temp = (const float*)d_in[4];
  const float* q = (const float*)d_in[5];

  float* xe = (float*)d_out;                 // [4,4096,64]
  float* e0 = xe + (size_t)BATCH * NN * DE;  // edges row 0 (indices)
  float* e1 = e0 + (size_t)BATCH * NN * KK;  // edges row 1 (rows)
  float* lp = e1 + (size_t)BATCH * NN * KK;  // logprobs

  const int ROWS = BATCH * NN;  // 16384
  char* ws = (char*)d_ws;
  float* sq = (float*)ws;  // 64 KB
  char* buf = ws + 65536;
  // need(S) = 64K + S*ROWS*(16*4 + 16*2)
  auto need = [&](size_t s) { return (size_t)65536 + s * (size_t)ROWS * 96; };
  int segs = (ws_size >= need(16)) ? 16 : (ws_size >= need(8)) ? 8 : 4;

  embed_kernel<<<BATCH * NN / 4, 256, 0, stream>>>(x, W, bias, xe);
  sqnorm_kernel<<<ROWS / 256, 256, 0, stream>>>(xe, sq);

#define RUN(S)                                                                \
  {                                                                           \
    float* Bv = (float*)buf;                                                  \
    unsigned short* Bc = (unsigned short*)(buf + (size_t)S * ROWS * 64);      \
    topk_seg_kernel<S><<<(ROWS / 256) * S, 256, 0, stream>>>(xe, sq, q, temp, \
                                                             Bv, Bc);         \
    mergeB_kernel<S><<<ROWS / 256, 256, 0, stream>>>(Bv, Bc, e0, e1, lp);     \
  }
  if (segs == 16) RUN(16)
  else if (segs == 8) RUN(8)
  else RUN(4)
#undef RUN
}